// Round 1
// 966.758 us; speedup vs baseline: 1.0105x; 1.0105x over previous
//
#include <hip/hip_runtime.h>

// ---------- types ----------
typedef __bf16 bf16x8 __attribute__((ext_vector_type(8)));
typedef __bf16 bf16x4 __attribute__((ext_vector_type(4)));
typedef __bf16 bf16x2 __attribute__((ext_vector_type(2)));
typedef float  f32x4  __attribute__((ext_vector_type(4)));

#define T_TOK 4096   // B*S
#define EDIM 512
#define HDIM 1024
#define VOCAB 32000

// ---------- async global->LDS (16B per lane, lane-contiguous LDS dest) ----------
__device__ __forceinline__ void async_copy16(const void* g, void* l) {
    __builtin_amdgcn_global_load_lds(
        (const __attribute__((address_space(1))) unsigned int*)g,
        (__attribute__((address_space(3))) unsigned int*)l, 16, 0, 0);
}

// ---------- fp32 -> bf16 convert ----------
__global__ void cvt_f32_bf16(const float4* __restrict__ src, bf16x4* __restrict__ dst, int n4) {
    int i = blockIdx.x * blockDim.x + threadIdx.x;
    if (i < n4) {
        float4 v = src[i];
        bf16x4 o = { (__bf16)v.x, (__bf16)v.y, (__bf16)v.z, (__bf16)v.w };
        dst[i] = o;
    }
}

// ---------- block reduce (sum of two values across 256 threads, broadcast) ----------
__device__ __forceinline__ void breduce2(float& s1, float& s2, float* sh) {
    #pragma unroll
    for (int off = 32; off >= 1; off >>= 1) {
        s1 += __shfl_xor(s1, off);
        s2 += __shfl_xor(s2, off);
    }
    int wid = threadIdx.x >> 6;
    __syncthreads();                     // protect sh reuse across calls
    if ((threadIdx.x & 63) == 0) { sh[wid] = s1; sh[4 + wid] = s2; }
    __syncthreads();
    s1 = sh[0] + sh[1] + sh[2] + sh[3];
    s2 = sh[4] + sh[5] + sh[6] + sh[7];
}

// ---------- embedding gather + LN; writes tok_f32, ctx_f32(=0), h_bf16=[0|tok] ----------
__global__ void embed_ln(const int* __restrict__ ids, const float* __restrict__ tab,
                         const float* __restrict__ g, const float* __restrict__ b,
                         float* __restrict__ tok, float* __restrict__ ctx,
                         __bf16* __restrict__ h) {
    __shared__ float sh[8];
    const int t = blockIdx.x, tid = threadIdx.x;   // 256 threads, 2 elems each
    const float2* row = (const float2*)(tab + (size_t)ids[t] * EDIM);
    float2 v = row[tid];
    float s1 = v.x + v.y;
    float s2 = v.x * v.x + v.y * v.y;
    breduce2(s1, s2, sh);
    const float mean = s1 * (1.0f / EDIM);
    const float var  = s2 * (1.0f / EDIM) - mean * mean;
    const float rstd = rsqrtf(var + 1e-5f);
    float2 gg = ((const float2*)g)[tid];
    float2 bb = ((const float2*)b)[tid];
    float y0 = (v.x - mean) * rstd * gg.x + bb.x;
    float y1 = (v.y - mean) * rstd * gg.y + bb.y;
    ((float2*)(tok + (size_t)t * EDIM))[tid] = make_float2(y0, y1);
    ((float2*)(ctx + (size_t)t * EDIM))[tid] = make_float2(0.f, 0.f);
    __bf16* hrow = h + (size_t)t * HDIM;
    ((bf16x2*)hrow)[tid]         = bf16x2{ (__bf16)0.f, (__bf16)0.f };      // ctx half
    ((bf16x2*)(hrow + EDIM))[tid] = bf16x2{ (__bf16)y0, (__bf16)y1 };       // tok half
}

// ---------- residual + LN for one block; updates ctx/tok masters, writes next h_bf16 ----------
__global__ void resid_ln(const float* __restrict__ h32, float* __restrict__ ctx,
                         float* __restrict__ tok,
                         const float* __restrict__ cg, const float* __restrict__ cb,
                         const float* __restrict__ tg, const float* __restrict__ tb,
                         __bf16* __restrict__ hn) {
    __shared__ float sh[8];
    const int t = blockIdx.x, tid = threadIdx.x;
    const float2* hrow = (const float2*)(h32 + (size_t)t * HDIM);
    __bf16* hnrow = hn + (size_t)t * HDIM;

    // ctx half: ctx = LN(ctx + h[:, :512])
    {
        float2 c  = ((float2*)(ctx + (size_t)t * EDIM))[tid];
        float2 hv = hrow[tid];
        float x0 = c.x + hv.x, x1 = c.y + hv.y;
        float s1 = x0 + x1, s2 = x0 * x0 + x1 * x1;
        breduce2(s1, s2, sh);
        const float mean = s1 * (1.0f / EDIM);
        const float rstd = rsqrtf(s2 * (1.0f / EDIM) - mean * mean + 1e-5f);
        float2 gg = ((const float2*)cg)[tid];
        float2 bb = ((const float2*)cb)[tid];
        float y0 = (x0 - mean) * rstd * gg.x + bb.x;
        float y1 = (x1 - mean) * rstd * gg.y + bb.y;
        ((float2*)(ctx + (size_t)t * EDIM))[tid] = make_float2(y0, y1);
        ((bf16x2*)hnrow)[tid] = bf16x2{ (__bf16)y0, (__bf16)y1 };
    }
    // tok half: tok = LN(tok + h[:, 512:])
    {
        float2 tv = ((float2*)(tok + (size_t)t * EDIM))[tid];
        float2 hv = hrow[256 + tid];
        float x0 = tv.x + hv.x, x1 = tv.y + hv.y;
        float s1 = x0 + x1, s2 = x0 * x0 + x1 * x1;
        breduce2(s1, s2, sh);
        const float mean = s1 * (1.0f / EDIM);
        const float rstd = rsqrtf(s2 * (1.0f / EDIM) - mean * mean + 1e-5f);
        float2 gg = ((const float2*)tg)[tid];
        float2 bb = ((const float2*)tb)[tid];
        float y0 = (x0 - mean) * rstd * gg.x + bb.x;
        float y1 = (x1 - mean) * rstd * gg.y + bb.y;
        ((float2*)(tok + (size_t)t * EDIM))[tid] = make_float2(y0, y1);
        ((bf16x2*)(hnrow + EDIM))[tid] = bf16x2{ (__bf16)y0, (__bf16)y1 };
    }
}

// ---------- bf16 GEMM, B^T layout: C[m][n] = sum_k A[m][k] * B[n][k] (+bias, opt relu) ----------
// 128x128 block tile, 4 waves (2x2), each wave 64x64 via 4x4 mfma_f32_16x16x32_bf16, BK=32.
__global__ __launch_bounds__(256, 2)
void gemm_bt(const __bf16* __restrict__ A, int lda,
             const __bf16* __restrict__ B, int ldb,
             const float* __restrict__ bias,
             __bf16* __restrict__ Cb, float* __restrict__ Cf,
             int ldc, int K, int do_relu) {
    __shared__ __align__(16) __bf16 sA[128 * 32];
    __shared__ __align__(16) __bf16 sB[128 * 32];
    const int tid = threadIdx.x;
    const int m0 = blockIdx.x * 128, n0 = blockIdx.y * 128;
    const int wid = tid >> 6, lane = tid & 63;
    const int wm = (wid >> 1) * 64, wn = (wid & 1) * 64;
    const int lr = lane & 15, lq = lane >> 4;

    f32x4 acc[4][4] = {};

    const __bf16* Abase = A + (size_t)m0 * lda;
    const __bf16* Bbase = B + (size_t)n0 * ldb;
    const int r0 = tid >> 2;      // staging row 0..63 (and +64)
    const int q0 = tid & 3;       // 16B chunk within BK=32

    for (int k0 = 0; k0 < K; k0 += 32) {
        const __bf16* Ak = Abase + k0 + q0 * 8;
        const __bf16* Bk = Bbase + k0 + q0 * 8;
        async_copy16(Ak + (size_t)r0 * lda,        sA + (size_t)tid * 8);
        async_copy16(Ak + (size_t)(r0 + 64) * lda, sA + (size_t)(tid + 256) * 8);
        async_copy16(Bk + (size_t)r0 * ldb,        sB + (size_t)tid * 8);
        async_copy16(Bk + (size_t)(r0 + 64) * ldb, sB + (size_t)(tid + 256) * 8);
        __syncthreads();   // drains vmcnt -> LDS valid

        bf16x8 af[4], bfr[4];
        #pragma unroll
        for (int mi = 0; mi < 4; mi++)
            af[mi] = *(const bf16x8*)(sA + (wm + mi * 16 + lr) * 32 + lq * 8);
        #pragma unroll
        for (int ni = 0; ni < 4; ni++)
            bfr[ni] = *(const bf16x8*)(sB + (wn + ni * 16 + lr) * 32 + lq * 8);
        #pragma unroll
        for (int mi = 0; mi < 4; mi++)
            #pragma unroll
            for (int ni = 0; ni < 4; ni++)
                acc[mi][ni] = __builtin_amdgcn_mfma_f32_16x16x32_bf16(
                    af[mi], bfr[ni], acc[mi][ni], 0, 0, 0);
        __syncthreads();   // all reads done before next stage overwrites
    }

    // epilogue: D row=(lane>>4)*4+reg, col=lane&15
    #pragma unroll
    for (int mi = 0; mi < 4; mi++) {
        const int rbase = m0 + wm + mi * 16 + lq * 4;
        #pragma unroll
        for (int ni = 0; ni < 4; ni++) {
            const int col = n0 + wn + ni * 16 + lr;
            const float bv = bias[col];
            #pragma unroll
            for (int r = 0; r < 4; r++) {
                float v = acc[mi][ni][r] + bv;
                if (do_relu) v = fmaxf(v, 0.f);
                const size_t idx = (size_t)(rbase + r) * ldc + col;
                if (Cf) Cf[idx] = v;
                if (Cb) Cb[idx] = (__bf16)v;
            }
        }
    }
}

// ================== 256x256 8-phase pipelined GEMM for the vocab projection ==================
// C[m][n] = sum_{k<512} A[m][k]*B[n][k] + bias[n].  A: lda=HDIM (tok half of hA), B: ldb=EDIM.
// 512 threads = 8 waves (2M x 4N); per-wave 128x64 output (8x4 frags of 16x16, BK=64 -> 2 kslices).
// LDS 128 KiB: A[2buf][2half][128][64] bf16 + B same. Stage granularity = half-tile (16 KiB,
// 2 global_load_lds per thread). Slot schedule (phase q of tile u):
//   q0: read B(all)+A-quad0, stage A-half0(u+1)   [A slot of buf^1 freed after q3 of tile u-1]
//   q1: read A-quad1,        stage A-half1(u+1)
//   q2: read A-quad2,        stage B-half0(u+2)   [B slots of this buf freed after q0 of tile u]
//   q3: read A-quad3,        stage B-half1(u+2), s_waitcnt vmcnt(4)  <- counted, never 0 (T4)
// At each tile boundary the 4 allowed-outstanding loads are exactly B(u+2) (not needed yet).
// T2 swizzle: LDS 16B-granule g at (row, c) stored at physical c^(row&7); global source is
// inverse-permuted so global_load_lds dest stays linear (rule 21); ds_read applies same XOR.
#define NKT 8   // 512 / 64

__device__ __forceinline__ void stage_half(const __bf16* __restrict__ gsrc, int ld,
                                           __bf16* __restrict__ lds_half, int tid) {
    #pragma unroll
    for (int c = 0; c < 2; c++) {
        const int g   = tid + c * 512;        // granule 0..1023 (128 rows x 8 granules)
        const int row = g >> 3;
        const int lc  = (g & 7) ^ (row & 7);  // inverse-swizzled logical column
        async_copy16(gsrc + (size_t)row * ld + lc * 8, lds_half + (size_t)g * 8);
    }
}

__global__ __launch_bounds__(512, 2)
void gemm_logits(const __bf16* __restrict__ A, const __bf16* __restrict__ B,
                 const float* __restrict__ bias, float* __restrict__ C) {
    __shared__ __align__(16) __bf16 sA[4 * 128 * 64];   // [buf*2+half][row][64]
    __shared__ __align__(16) __bf16 sB[4 * 128 * 64];
    const int tid = threadIdx.x;

    // T1: bijective XCD swizzle. 2000 blocks = 8 chunks of 250; chunk = 2 m-tiles x 125 n-tiles
    const int wg  = blockIdx.x;
    const int swz = (wg & 7) * 250 + (wg >> 3);
    const int cc  = swz % 250;
    const int mt  = (swz / 250) * 2 + (cc & 1);   // 0..15
    const int nt  = cc >> 1;                      // 0..124
    const int m0 = mt << 8, n0 = nt << 8;

    const int wid = tid >> 6, lane = tid & 63;
    const int wm  = (wid >> 2) << 7;    // 0 / 128
    const int wn  = (wid & 3) << 6;     // 0 / 64 / 128 / 192
    const int lr  = lane & 15, lq = lane >> 4;
    const int ah  = wm >> 7;            // the only A-half this wave reads
    const int bh  = wn >> 7;            // the only B-half this wave reads
    const int br0 = wn & 64;

    f32x4 acc[8][4] = {};

    const __bf16* Abase = A + (size_t)m0 * HDIM;
    const __bf16* Bbase = B + (size_t)n0 * EDIM;

    // prologue: A0(0) A1(0) B0(0) B1(0) B0(1) B1(1); allow B(1) (4 loads) outstanding
    stage_half(Abase,                           HDIM, sA,            tid);
    stage_half(Abase + (size_t)128 * HDIM,      HDIM, sA + 8192,     tid);
    stage_half(Bbase,                           EDIM, sB,            tid);
    stage_half(Bbase + (size_t)128 * EDIM,      EDIM, sB + 8192,     tid);
    stage_half(Bbase + 64,                      EDIM, sB + 2 * 8192, tid);
    stage_half(Bbase + (size_t)128 * EDIM + 64, EDIM, sB + 3 * 8192, tid);
    asm volatile("s_waitcnt vmcnt(4)" ::: "memory");
    __builtin_amdgcn_s_barrier();

    #pragma unroll 1
    for (int u = 0; u < NKT; u++) {
        const int par = u & 1, nxt = par ^ 1;
        const __bf16* sAh = sA + (par * 2 + ah) * 8192;
        const __bf16* sBh = sB + (par * 2 + bh) * 8192;
        bf16x8 bfr[4][2];
        #pragma unroll
        for (int q = 0; q < 4; q++) {
            if (q == 0) {   // B frags for the whole tile, held in regs across phases
                #pragma unroll
                for (int ni = 0; ni < 4; ni++)
                    #pragma unroll
                    for (int ks = 0; ks < 2; ks++) {
                        const int row = br0 + ni * 16 + lr;
                        bfr[ni][ks] = *(const bf16x8*)(sBh + (row << 6) +
                                        (((ks * 4 + lq) ^ (row & 7)) << 3));
                    }
            }
            bf16x8 af[2][2];
            #pragma unroll
            for (int mi = 0; mi < 2; mi++)
                #pragma unroll
                for (int ks = 0; ks < 2; ks++) {
                    const int row = (q * 2 + mi) * 16 + lr;
                    af[mi][ks] = *(const bf16x8*)(sAh + (row << 6) +
                                    (((ks * 4 + lq) ^ (row & 7)) << 3));
                }
            if (q == 0 && u + 1 < NKT)
                stage_half(Abase + (u + 1) * 64,                      HDIM, sA + (nxt * 2) * 8192,     tid);
            if (q == 1 && u + 1 < NKT)
                stage_half(Abase + (size_t)128 * HDIM + (u + 1) * 64, HDIM, sA + (nxt * 2 + 1) * 8192, tid);
            if (q == 2 && u + 2 < NKT)
                stage_half(Bbase + (u + 2) * 64,                      EDIM, sB + (par * 2) * 8192,     tid);
            if (q == 3 && u + 2 < NKT)
                stage_half(Bbase + (size_t)128 * EDIM + (u + 2) * 64, EDIM, sB + (par * 2 + 1) * 8192, tid);
            __builtin_amdgcn_s_barrier();
            asm volatile("s_waitcnt lgkmcnt(0)" ::: "memory");
            __builtin_amdgcn_s_setprio(1);
            #pragma unroll
            for (int mi = 0; mi < 2; mi++)
                #pragma unroll
                for (int ni = 0; ni < 4; ni++)
                    #pragma unroll
                    for (int ks = 0; ks < 2; ks++)
                        acc[q * 2 + mi][ni] = __builtin_amdgcn_mfma_f32_16x16x32_bf16(
                            af[mi][ks], bfr[ni][ks], acc[q * 2 + mi][ni], 0, 0, 0);
            __builtin_amdgcn_s_setprio(0);
            if (q == 3) {
                if (u < NKT - 2)       { asm volatile("s_waitcnt vmcnt(4)" ::: "memory"); }
                else if (u == NKT - 2) { asm volatile("s_waitcnt vmcnt(0)" ::: "memory"); }
            }
            __builtin_amdgcn_s_barrier();
        }
    }

    // epilogue: D row=(lane>>4)*4+reg, col=lane&15
    #pragma unroll
    for (int mi = 0; mi < 8; mi++) {
        const int row = m0 + wm + mi * 16 + lq * 4;
        #pragma unroll
        for (int ni = 0; ni < 4; ni++) {
            const int col = n0 + wn + ni * 16 + lr;
            const float bv = bias[col];
            #pragma unroll
            for (int r = 0; r < 4; r++)
                C[(size_t)(row + r) * VOCAB + col] = acc[mi][ni][r] + bv;
        }
    }
}

extern "C" void kernel_launch(void* const* d_in, const int* in_sizes, int n_in,
                              void* d_out, int out_size, void* d_ws, size_t ws_size,
                              hipStream_t stream) {
    const int*   ids  = (const int*)d_in[0];
    const float* tab  = (const float*)d_in[1];
    const float* en_g = (const float*)d_in[2];
    const float* en_b = (const float*)d_in[3];
    const float* Wb   = (const float*)d_in[4];   // [3][2][1024][1024]
    const float* bb   = (const float*)d_in[5];   // [3][2][1024]
    const float* cn_g = (const float*)d_in[6];
    const float* cn_b = (const float*)d_in[7];
    const float* tn_g = (const float*)d_in[8];
    const float* tn_b = (const float*)d_in[9];
    const float* outW = (const float*)d_in[10];  // [32000][512]
    const float* outb = (const float*)d_in[11];
    float* out = (float*)d_out;

    char* ws = (char*)d_ws;
    float*  tok  = (float*)ws;  ws += (size_t)T_TOK * EDIM * 4;
    float*  ctx  = (float*)ws;  ws += (size_t)T_TOK * EDIM * 4;
    float*  h32  = (float*)ws;  ws += (size_t)T_TOK * HDIM * 4;
    __bf16* hA   = (__bf16*)ws; ws += (size_t)T_TOK * HDIM * 2;
    __bf16* hB   = (__bf16*)ws; ws += (size_t)T_TOK * HDIM * 2;
    __bf16* Wb16 = (__bf16*)ws; ws += (size_t)6 * HDIM * HDIM * 2;
    __bf16* oW16 = (__bf16*)ws; ws += (size_t)VOCAB * EDIM * 2;

    const int nW  = 6 * HDIM * HDIM;     // 6,291,456
    const int nOW = VOCAB * EDIM;        // 16,384,000
    cvt_f32_bf16<<<(nW / 4 + 255) / 256, 256, 0, stream>>>((const float4*)Wb, (bf16x4*)Wb16, nW / 4);
    cvt_f32_bf16<<<(nOW / 4 + 255) / 256, 256, 0, stream>>>((const float4*)outW, (bf16x4*)oW16, nOW / 4);

    embed_ln<<<T_TOK, 256, 0, stream>>>(ids, tab, en_g, en_b, tok, ctx, hA);

    for (int bi = 0; bi < 3; bi++) {
        if (bi == 0) {
            // ctx half of h is identically zero for the first layer: only the tok half
            // (k in [512,1024)) contributes -> run with K=512 against W[:, 512:].
            gemm_bt<<<dim3(32, 8), 256, 0, stream>>>(
                hA + EDIM, HDIM, Wb16 + 512, HDIM,
                bb, hB, nullptr, HDIM, 512, 1);
        } else {
            gemm_bt<<<dim3(32, 8), 256, 0, stream>>>(
                hA, HDIM, Wb16 + (size_t)(bi * 2 + 0) * HDIM * HDIM, HDIM,
                bb + (size_t)(bi * 2 + 0) * HDIM, hB, nullptr, HDIM, HDIM, 1);
        }
        // layer 1: fp32 out (residual input)
        gemm_bt<<<dim3(32, 8), 256, 0, stream>>>(
            hB, HDIM, Wb16 + (size_t)(bi * 2 + 1) * HDIM * HDIM, HDIM,
            bb + (size_t)(bi * 2 + 1) * HDIM, nullptr, h32, HDIM, HDIM, 1);
        resid_ln<<<T_TOK, 256, 0, stream>>>(
            h32, ctx, tok, cn_g + bi * EDIM, cn_b + bi * EDIM,
            tn_g + bi * EDIM, tn_b + bi * EDIM, hA);
    }

    // logits = tok @ out_W^T + out_b ; tok (bf16) lives in hA[:, 512:]
    gemm_logits<<<2000, 512, 0, stream>>>(hA + EDIM, oW16, outb, out);
}